// Round 1
// baseline (421.035 us; speedup 1.0000x reference)
//
#include <hip/hip_runtime.h>
#include <hip/hip_bf16.h>

#define TWO_PI_F 6.283185307179586f

typedef __attribute__((ext_vector_type(4))) float f32x4;
typedef __attribute__((ext_vector_type(8))) short s16x8;

__device__ __forceinline__ short f2bf(float f) {
    union { float f; unsigned u; } a; a.f = f;
    unsigned r = a.u + 0x7fffu + ((a.u >> 16) & 1u);
    return (short)(r >> 16);
}

// ---------- kernel 0: weights -> bf16, W4 zero-padded to [16][128] ----------
__global__ void k_prep_w(const float* __restrict__ W0, const float* __restrict__ W1,
                         const float* __restrict__ W2, const float* __restrict__ W3,
                         const float* __restrict__ W4, short* __restrict__ wbf) {
    int i = blockIdx.x * 256 + threadIdx.x;
    if (i < 65536) {
        int w = i >> 14;
        const float* src = (w == 0) ? W0 : (w == 1) ? W1 : (w == 2) ? W2 : W3;
        wbf[i] = f2bf(src[i & 16383]);
    } else if (i < 65536 + 2048) {
        int j = i - 65536;
        int row = j >> 7, col = j & 127;
        wbf[i] = f2bf(row == 0 ? W4[col] : 0.0f);
    }
}

// ---------- kernel T: 1D phase tables  tab[n][{cosA,sinA,cosB,sinB}][128] ----------
__global__ void k_tables(const float* __restrict__ ktraj, float* __restrict__ tab) {
    int g = blockIdx.x * 256 + threadIdx.x;   // 2048 * 256
    int n = g >> 8, s = g & 255;
    if (s < 128) {
        float a = ktraj[n] * (float)s;                 // kx * x
        tab[n * 512 + s]       = __cosf(a);
        tab[n * 512 + 128 + s] = __sinf(a);
    } else {
        int y = s - 128;
        float a = ktraj[2048 + n] * (float)y;          // ky * y
        tab[n * 512 + 256 + y] = __cosf(a);
        tab[n * 512 + 384 + y] = __sinf(a);
    }
}

// ---------- kernel 1: fused encode + SIREN + (vol - image), barrier-free ----------
// Block = 256 thr (4 waves). Each wave privately owns 64 LDS rows [64][128] bf16
// (stride 256B, XOR-swizzle (row&7)<<4 on byte offset -> 2-way max on ds_read_b128).
__launch_bounds__(256, 2)
__global__ void k_siren(const float* __restrict__ Bmat,
                        const float* __restrict__ b0, const float* __restrict__ b1,
                        const float* __restrict__ b2, const float* __restrict__ b3,
                        const float* __restrict__ b4,
                        const short* __restrict__ wbf,
                        const float* __restrict__ image,
                        float* __restrict__ d_nat) {
    __shared__ alignas(16) char Abuf[256 * 256];   // 64 KB
    const int tid  = threadIdx.x;
    const int lane = tid & 63;
    const int w    = tid >> 6;
    const int l15  = lane & 15;
    const int l4   = lane >> 4;
    const int nbase = blockIdx.x * 256;

    // ---- encode: feat = [sin(p_e) e<64 | cos(p_e)] ----
    {
        int n = nbase + tid;
        int xi = n >> 13, yi = (n >> 6) & 127, zi = n & 63;
        float gx = (xi + 0.5f) * (TWO_PI_F / 128.0f);
        float gy = (yi + 0.5f) * (TWO_PI_F / 128.0f);
        float gz = (zi + 0.5f) * (TWO_PI_F / 64.0f);
        int rswz = (tid & 7) << 4;
        char* rowp = Abuf + tid * 256;
        #pragma unroll
        for (int eb = 0; eb < 64; eb += 8) {
            float p[8];
            #pragma unroll
            for (int j = 0; j < 8; j++) {
                int e = eb + j;
                p[j] = gx * Bmat[e * 3 + 0] + gy * Bmat[e * 3 + 1] + gz * Bmat[e * 3 + 2];
            }
            s16x8 vs, vc;
            #pragma unroll
            for (int j = 0; j < 8; j++) {
                vs[j] = f2bf(__sinf(p[j]));
                vc[j] = f2bf(__cosf(p[j]));
            }
            *(s16x8*)(rowp + ((2 * eb) ^ rswz))       = vs;   // cols eb..eb+7
            *(s16x8*)(rowp + ((128 + 2 * eb) ^ rswz)) = vc;   // cols 64+eb..
        }
    }
    // no __syncthreads(): LDS rows are wave-private throughout.

    // ---- 4 hidden layers: z = A @ W^T ; A <- sin(30*(z+b)) ----
    #pragma unroll 1
    for (int layer = 0; layer < 4; layer++) {
        const short* W = wbf + layer * 16384;
        const float* bias = (layer == 0) ? b0 : (layer == 1) ? b1 : (layer == 2) ? b2 : b3;
        f32x4 acc[4][8];
        #pragma unroll
        for (int rt = 0; rt < 4; rt++)
            #pragma unroll
            for (int nt = 0; nt < 8; nt++)
                acc[rt][nt] = (f32x4){0.f, 0.f, 0.f, 0.f};

        #pragma unroll
        for (int ks = 0; ks < 4; ks++) {
            s16x8 bfrag[8];
            #pragma unroll
            for (int nt = 0; nt < 8; nt++)   // B[k][n] = W[n][k], 16B contiguous per lane
                bfrag[nt] = *(const s16x8*)(W + (nt * 16 + l15) * 128 + ks * 32 + l4 * 8);
            #pragma unroll
            for (int rt = 0; rt < 4; rt++) {
                s16x8 af = *(const s16x8*)(Abuf + (w * 64 + rt * 16 + l15) * 256 +
                                           ((ks * 64 + l4 * 16) ^ ((l15 & 7) << 4)));
                #pragma unroll
                for (int nt = 0; nt < 8; nt++)
                    acc[rt][nt] = __builtin_amdgcn_mfma_f32_16x16x32_bf16(af, bfrag[nt], acc[rt][nt], 0, 0, 0);
            }
        }
        // activation + writeback (D: row=(l>>4)*4+jj, col=l&15)
        #pragma unroll
        for (int nt = 0; nt < 8; nt++) {
            float bv = bias[nt * 16 + l15];
            #pragma unroll
            for (int rt = 0; rt < 4; rt++) {
                #pragma unroll
                for (int jj = 0; jj < 4; jj++) {
                    float h = __sinf(30.0f * (acc[rt][nt][jj] + bv));
                    int r = l4 * 4 + jj;
                    *(short*)(Abuf + (w * 64 + rt * 16 + r) * 256 +
                              ((nt * 32 + l15 * 2) ^ ((r & 7) << 4))) = f2bf(h);
                }
            }
        }
    }

    // ---- final layer (W4 padded into 16 cols, only col 0 valid) + diff vs image ----
    {
        const short* W = wbf + 65536;
        f32x4 acc4[4];
        #pragma unroll
        for (int rt = 0; rt < 4; rt++) acc4[rt] = (f32x4){0.f, 0.f, 0.f, 0.f};
        #pragma unroll
        for (int ks = 0; ks < 4; ks++) {
            s16x8 bfrag = *(const s16x8*)(W + l15 * 128 + ks * 32 + l4 * 8);
            #pragma unroll
            for (int rt = 0; rt < 4; rt++) {
                s16x8 af = *(const s16x8*)(Abuf + (w * 64 + rt * 16 + l15) * 256 +
                                           ((ks * 64 + l4 * 16) ^ ((l15 & 7) << 4)));
                acc4[rt] = __builtin_amdgcn_mfma_f32_16x16x32_bf16(af, bfrag, acc4[rt], 0, 0, 0);
            }
        }
        if (l15 == 0) {
            float b4v = b4[0];
            #pragma unroll
            for (int rt = 0; rt < 4; rt++) {
                int row = w * 64 + rt * 16 + l4 * 4;
                int n = nbase + row;
                const f32x4 img = *(const f32x4*)(image + n);
                f32x4 dv;
                #pragma unroll
                for (int jj = 0; jj < 4; jj++) dv[jj] = acc4[rt][jj] + b4v - img[jj];
                *(f32x4*)(d_nat + n) = dv;
            }
        }
    }
}

// ---------- kernel 1.5: d_nat [x][y][z] fp32 -> d_proj [z][x*128+y] bf16 ----------
__global__ void k_transpose(const float* __restrict__ d_nat, short* __restrict__ d_proj) {
    __shared__ float t[128][65];
    int x = blockIdx.x;
    for (int i = threadIdx.x; i < 8192; i += 256)
        t[i >> 6][i & 63] = d_nat[x * 8192 + i];
    __syncthreads();
    for (int i = threadIdx.x; i < 8192; i += 256) {
        int z = i >> 7, y = i & 127;
        d_proj[z * 16384 + x * 128 + y] = f2bf(t[y][z]);
    }
}

// ---------- kernel 2: NUDFT GEMM (M=64 z, N=2048 k-samples, K=16384 pixels) ----------
// grid = 64 nblk x 8 ksplit. Per block: 32 n-cols, 2048 pixels; 4 waves split pixels.
// B built on the fly: cosP = cA*cB - sA*sB, sinP = sA*cB + cA*sB from LDS tables.
__launch_bounds__(256, 2)
__global__ void k_project(const short* __restrict__ d_proj, const float* __restrict__ tab,
                          float* __restrict__ part) {
    __shared__ alignas(16) float lt[4 * 32 * 132];   // 67584 B; reused as reduce buffer
    const int tid  = threadIdx.x;
    const int lane = tid & 63;
    const int w    = tid >> 6;
    const int l15  = lane & 15;
    const int l4   = lane >> 4;
    const int nblk = blockIdx.x & 63;
    const int ksp  = blockIdx.x >> 6;
    const int nbase = nblk * 32;

    for (int i = tid; i < 16384; i += 256) {
        int nl = i >> 9, r = i & 511;
        int t = r >> 7, e = r & 127;
        lt[(t * 32 + nl) * 132 + e] = tab[(nbase + nl) * 512 + r];
    }
    __syncthreads();

    f32x4 ar[4][2], ai[4][2];
    #pragma unroll
    for (int rt = 0; rt < 4; rt++)
        #pragma unroll
        for (int nt = 0; nt < 2; nt++) {
            ar[rt][nt] = (f32x4){0.f, 0.f, 0.f, 0.f};
            ai[rt][nt] = (f32x4){0.f, 0.f, 0.f, 0.f};
        }

    const int p2base = ksp * 2048 + w * 512;
    #pragma unroll 1
    for (int ks = 0; ks < 16; ks++) {
        int p2c = p2base + ks * 32;
        s16x8 afr[4];
        #pragma unroll
        for (int rt = 0; rt < 4; rt++)
            afr[rt] = *(const s16x8*)(d_proj + (rt * 16 + l15) * 16384 + p2c + l4 * 8);
        int p2 = p2c + l4 * 8;
        int x = p2 >> 7, y0 = p2 & 127;
        #pragma unroll
        for (int nt = 0; nt < 2; nt++) {
            int nl = nt * 16 + l15;
            float cA = lt[nl * 132 + x];
            float sA = lt[(32 + nl) * 132 + x];
            const float* cB = &lt[(64 + nl) * 132 + y0];
            const float* sB = &lt[(96 + nl) * 132 + y0];
            s16x8 bc, bs;
            #pragma unroll
            for (int j = 0; j < 8; j++) {
                float cb = cB[j], sb = sB[j];
                bc[j] = f2bf(cA * cb - sA * sb);
                bs[j] = f2bf(sA * cb + cA * sb);
            }
            #pragma unroll
            for (int rt = 0; rt < 4; rt++) {
                ar[rt][nt] = __builtin_amdgcn_mfma_f32_16x16x32_bf16(afr[rt], bc, ar[rt][nt], 0, 0, 0);
                ai[rt][nt] = __builtin_amdgcn_mfma_f32_16x16x32_bf16(afr[rt], bs, ai[rt][nt], 0, 0, 0);
            }
        }
    }
    __syncthreads();   // tables dead; reuse lt as reduce buffer [4][64][64]
    float* red = lt;
    #pragma unroll
    for (int rt = 0; rt < 4; rt++)
        #pragma unroll
        for (int nt = 0; nt < 2; nt++)
            #pragma unroll
            for (int jj = 0; jj < 4; jj++) {
                int z = rt * 16 + l4 * 4 + jj;
                int q = nt * 16 + l15;
                red[(w * 64 + z) * 64 + q * 2 + 0] = ar[rt][nt][jj];
                red[(w * 64 + z) * 64 + q * 2 + 1] = ai[rt][nt][jj];
            }
    __syncthreads();
    for (int i = tid; i < 4096; i += 256) {
        int z = i >> 6, q = i & 63;
        float s = red[z * 64 + q] + red[4096 + z * 64 + q] + red[8192 + z * 64 + q] + red[12288 + z * 64 + q];
        part[((ksp * 64 + z) * 2048 + nbase + (q >> 1)) * 2 + (q & 1)] = s;
    }
}

// ---------- kernel 3: sum K-split partials, square, reduce to loss ----------
__global__ void k_loss(const float* __restrict__ part, float* __restrict__ out) {
    int g = blockIdx.x * 256 + threadIdx.x;   // 131072 (z,n) pairs
    int z = g >> 11, n = g & 2047;
    float r = 0.f, im = 0.f;
    #pragma unroll
    for (int ksp = 0; ksp < 8; ksp++) {
        const float2 v = *(const float2*)(part + ((ksp * 64 + z) * 2048 + n) * 2);
        r += v.x; im += v.y;
    }
    float val = r * r + im * im;
    #pragma unroll
    for (int o = 32; o > 0; o >>= 1) val += __shfl_xor(val, o);
    __shared__ float sred[4];
    if ((threadIdx.x & 63) == 0) sred[threadIdx.x >> 6] = val;
    __syncthreads();
    if (threadIdx.x == 0)
        atomicAdd(out, (sred[0] + sred[1] + sred[2] + sred[3]) * (0.5f / 131072.0f));
}

extern "C" void kernel_launch(void* const* d_in, const int* in_sizes, int n_in,
                              void* d_out, int out_size, void* d_ws, size_t ws_size,
                              hipStream_t stream) {
    const float* Bmat  = (const float*)d_in[1];
    const float* W0    = (const float*)d_in[2];
    const float* b0    = (const float*)d_in[3];
    const float* W1    = (const float*)d_in[4];
    const float* b1    = (const float*)d_in[5];
    const float* W2    = (const float*)d_in[6];
    const float* b2    = (const float*)d_in[7];
    const float* W3    = (const float*)d_in[8];
    const float* b3    = (const float*)d_in[9];
    const float* W4    = (const float*)d_in[10];
    const float* b4    = (const float*)d_in[11];
    const float* image = (const float*)d_in[12];
    const float* ktraj = (const float*)d_in[13];

    char* ws = (char*)d_ws;
    short* wbf    = (short*)(ws);                  // 135168 B
    float* tab    = (float*)(ws + (1u << 20));     // 4 MB
    float* d_nat  = (float*)(ws + (5u << 20));     // 4 MB
    short* d_proj = (short*)(ws + (9u << 20));     // 2 MB
    float* part   = (float*)(ws + (11u << 20));    // 8 MB  (total ~19 MB)
    float* outf   = (float*)d_out;

    hipLaunchKernelGGL(k_prep_w,    dim3(264),  dim3(256), 0, stream, W0, W1, W2, W3, W4, wbf);
    hipLaunchKernelGGL(k_tables,    dim3(2048), dim3(256), 0, stream, ktraj, tab);
    hipLaunchKernelGGL(k_siren,     dim3(4096), dim3(256), 0, stream, Bmat, b0, b1, b2, b3, b4, wbf, image, d_nat);
    hipLaunchKernelGGL(k_transpose, dim3(128),  dim3(256), 0, stream, d_nat, d_proj);
    hipLaunchKernelGGL(k_project,   dim3(512),  dim3(256), 0, stream, d_proj, tab, part);
    hipMemsetAsync(d_out, 0, sizeof(float), stream);
    hipLaunchKernelGGL(k_loss,      dim3(512),  dim3(256), 0, stream, part, outf);
}

// Round 2
// 276.684 us; speedup vs baseline: 1.5217x; 1.5217x over previous
//
#include <hip/hip_runtime.h>
#include <hip/hip_bf16.h>

#define K30REV 4.77464829275686f   /* 30/(2*pi) */

typedef __attribute__((ext_vector_type(4))) float f32x4;
typedef __attribute__((ext_vector_type(8))) short s16x8;

__device__ __forceinline__ short f2bf(float f) {
    union { float f; unsigned u; } a; a.f = f;
    unsigned r = a.u + 0x7fffu + ((a.u >> 16) & 1u);
    return (short)(r >> 16);
}

__device__ __forceinline__ unsigned pk2(float a, float b) {
    union { __hip_bfloat162 h; unsigned u; } cv;
    cv.h = __float22bfloat162_rn(make_float2(a, b));
    return cv.u;
}

// ---------- kernel 0: weights -> bf16, W4 zero-padded to [16][128], bias prescale ----------
__global__ void k_prep_w(const float* __restrict__ W0, const float* __restrict__ W1,
                         const float* __restrict__ W2, const float* __restrict__ W3,
                         const float* __restrict__ W4,
                         const float* __restrict__ b0, const float* __restrict__ b1,
                         const float* __restrict__ b2, const float* __restrict__ b3,
                         short* __restrict__ wbf, float* __restrict__ brev) {
    int i = blockIdx.x * 256 + threadIdx.x;
    if (i < 65536) {
        int w = i >> 14;
        const float* src = (w == 0) ? W0 : (w == 1) ? W1 : (w == 2) ? W2 : W3;
        wbf[i] = f2bf(src[i & 16383]);
    } else if (i < 65536 + 2048) {
        int j = i - 65536;
        int row = j >> 7, col = j & 127;
        wbf[i] = f2bf(row == 0 ? W4[col] : 0.0f);
    } else if (i < 65536 + 2048 + 512) {
        int j = i - (65536 + 2048);
        int l = j >> 7, col = j & 127;
        const float* src = (l == 0) ? b0 : (l == 1) ? b1 : (l == 2) ? b2 : b3;
        brev[j] = src[col] * K30REV;
    }
}

// ---------- kernel T: 1D phase tables  tab[n][{cosA,sinA,cosB,sinB}][128] ----------
__global__ void k_tables(const float* __restrict__ ktraj, float* __restrict__ tab) {
    int g = blockIdx.x * 256 + threadIdx.x;   // 2048 * 256
    int n = g >> 8, s = g & 255;
    if (s < 128) {
        float a = ktraj[n] * (float)s;                 // kx * x
        tab[n * 512 + s]       = __cosf(a);
        tab[n * 512 + 128 + s] = __sinf(a);
    } else {
        int y = s - 128;
        float a = ktraj[2048 + n] * (float)y;          // ky * y
        tab[n * 512 + 256 + y] = __cosf(a);
        tab[n * 512 + 384 + y] = __sinf(a);
    }
}

// ---------- kernel 1: fused encode + SIREN + (vol - image) ----------
// 512 thr = 8 waves as 2(row)x4(col) over a shared 256-row A tile in LDS.
// A stored row-major [256][128] bf16, stride 256B, XOR swizzle ((row&7)<<4) on byte col.
// MFMA operand-swapped: mfma(af=W rows, bf=A rows) -> D[n][r], lane: r=l15, n=l4*4+jj
// -> activation writeback is ds_write_b64 of 4 consecutive cols.
__launch_bounds__(512, 4)
__global__ void k_siren(const float* __restrict__ Bmat,
                        const float* __restrict__ brev,
                        const float* __restrict__ b4,
                        const short* __restrict__ wbf,
                        const float* __restrict__ image,
                        float* __restrict__ d_nat) {
    __shared__ alignas(16) char Abuf[256 * 256];   // 64 KB
    const int tid  = threadIdx.x;
    const int lane = tid & 63;
    const int w    = tid >> 6;
    const int wr   = w >> 2;        // row half: 128 rows
    const int wc   = w & 3;         // col quarter: 32 cols
    const int l15  = lane & 15;
    const int l4   = lane >> 4;
    const int nbase = blockIdx.x * 256;
    const int key  = (l15 & 7) << 4;

    // ---- encode (2 threads per row, 32 freqs each), phases in revolutions ----
    {
        int row = tid >> 1, half = tid & 1;
        int n = nbase + row;
        int xi = n >> 13, yi = (n >> 6) & 127, zi = n & 63;
        float gx = (xi + 0.5f) * (1.0f / 128.0f);
        float gy = (yi + 0.5f) * (1.0f / 128.0f);
        float gz = (zi + 0.5f) * (1.0f / 64.0f);
        char* rowp = Abuf + row * 256;
        int rkey = (row & 7) << 4;
        int ebase = half * 32;
        #pragma unroll
        for (int eb = 0; eb < 32; eb += 8) {
            float pr[8];
            #pragma unroll
            for (int j = 0; j < 8; j++) {
                int e = ebase + eb + j;
                pr[j] = gx * Bmat[e * 3 + 0] + gy * Bmat[e * 3 + 1] + gz * Bmat[e * 3 + 2];
            }
            unsigned vs[4], vc[4];
            #pragma unroll
            for (int j = 0; j < 4; j++) {
                vs[j] = pk2(__builtin_amdgcn_sinf(pr[2 * j]), __builtin_amdgcn_sinf(pr[2 * j + 1]));
                vc[j] = pk2(__builtin_amdgcn_cosf(pr[2 * j]), __builtin_amdgcn_cosf(pr[2 * j + 1]));
            }
            *(uint4*)(rowp + ((2 * (ebase + eb)) ^ rkey))       = *(uint4*)vs;   // sin cols
            *(uint4*)(rowp + ((128 + 2 * (ebase + eb)) ^ rkey)) = *(uint4*)vc;   // cos cols
        }
    }
    __syncthreads();

    // ---- 4 hidden layers ----
    #pragma unroll 1
    for (int layer = 0; layer < 4; layer++) {
        const short* W  = wbf + layer * 16384;
        const float* br = brev + layer * 128;
        f32x4 acc[8][2];
        #pragma unroll
        for (int rt = 0; rt < 8; rt++) {
            acc[rt][0] = (f32x4){0.f, 0.f, 0.f, 0.f};
            acc[rt][1] = (f32x4){0.f, 0.f, 0.f, 0.f};
        }
        #pragma unroll
        for (int ks = 0; ks < 4; ks++) {
            s16x8 af0 = *(const s16x8*)(W + (wc * 32 + l15) * 128 + ks * 32 + l4 * 8);
            s16x8 af1 = *(const s16x8*)(W + (wc * 32 + 16 + l15) * 128 + ks * 32 + l4 * 8);
            #pragma unroll
            for (int rt = 0; rt < 8; rt++) {
                s16x8 bf = *(const s16x8*)(Abuf + (wr * 128 + rt * 16 + l15) * 256 +
                                           ((ks * 64 + l4 * 16) ^ key));
                acc[rt][0] = __builtin_amdgcn_mfma_f32_16x16x32_bf16(af0, bf, acc[rt][0], 0, 0, 0);
                acc[rt][1] = __builtin_amdgcn_mfma_f32_16x16x32_bf16(af1, bf, acc[rt][1], 0, 0, 0);
            }
        }
        __syncthreads();   // all reads of A done before overwrite
        #pragma unroll
        for (int nt = 0; nt < 2; nt++) {
            f32x4 bb = *(const f32x4*)(br + wc * 32 + nt * 16 + l4 * 4);
            #pragma unroll
            for (int rt = 0; rt < 8; rt++) {
                float s0 = __builtin_amdgcn_sinf(fmaf(acc[rt][nt][0], K30REV, bb[0]));
                float s1 = __builtin_amdgcn_sinf(fmaf(acc[rt][nt][1], K30REV, bb[1]));
                float s2 = __builtin_amdgcn_sinf(fmaf(acc[rt][nt][2], K30REV, bb[2]));
                float s3 = __builtin_amdgcn_sinf(fmaf(acc[rt][nt][3], K30REV, bb[3]));
                uint2 pk; pk.x = pk2(s0, s1); pk.y = pk2(s2, s3);
                int r = wr * 128 + rt * 16 + l15;
                *(uint2*)(Abuf + r * 256 + ((wc * 64 + nt * 32 + l4 * 8) ^ key)) = pk;
            }
        }
        __syncthreads();   // writes visible before next layer reads
    }

    // ---- final layer (unswapped): af=A rows, bf=W4 padded; each wave does 2 row-tiles ----
    {
        const short* W = wbf + 65536;
        f32x4 acc4[2];
        acc4[0] = (f32x4){0.f, 0.f, 0.f, 0.f};
        acc4[1] = (f32x4){0.f, 0.f, 0.f, 0.f};
        #pragma unroll
        for (int ks = 0; ks < 4; ks++) {
            s16x8 bw = *(const s16x8*)(W + l15 * 128 + ks * 32 + l4 * 8);
            #pragma unroll
            for (int q = 0; q < 2; q++) {
                int r = wr * 128 + (wc * 2 + q) * 16 + l15;
                s16x8 af = *(const s16x8*)(Abuf + r * 256 + ((ks * 64 + l4 * 16) ^ key));
                acc4[q] = __builtin_amdgcn_mfma_f32_16x16x32_bf16(af, bw, acc4[q], 0, 0, 0);
            }
        }
        if (l15 == 0) {
            float b4v = b4[0];
            #pragma unroll
            for (int q = 0; q < 2; q++) {
                int row0 = wr * 128 + (wc * 2 + q) * 16 + l4 * 4;
                int n = nbase + row0;
                const f32x4 img = *(const f32x4*)(image + n);
                f32x4 dv;
                #pragma unroll
                for (int jj = 0; jj < 4; jj++) dv[jj] = acc4[q][jj] + b4v - img[jj];
                *(f32x4*)(d_nat + n) = dv;
            }
        }
    }
}

// ---------- kernel 1.5: d_nat [x][y][z] fp32 -> d_proj [z][x*128+y] bf16 ----------
__global__ void k_transpose(const float* __restrict__ d_nat, short* __restrict__ d_proj) {
    __shared__ float t[128][65];
    int x = blockIdx.x;
    for (int i = threadIdx.x; i < 8192; i += 256)
        t[i >> 6][i & 63] = d_nat[x * 8192 + i];
    __syncthreads();
    for (int i = threadIdx.x; i < 8192; i += 256) {
        int z = i >> 7, y = i & 127;
        d_proj[z * 16384 + x * 128 + y] = f2bf(t[y][z]);
    }
}

// ---------- kernel 2: NUDFT GEMM (M=64 z, N=2048 k-samples, K=16384 pixels) ----------
__launch_bounds__(256, 2)
__global__ void k_project(const short* __restrict__ d_proj, const float* __restrict__ tab,
                          float* __restrict__ part) {
    __shared__ alignas(16) float lt[4 * 32 * 132];   // 67584 B; reused as reduce buffer
    const int tid  = threadIdx.x;
    const int lane = tid & 63;
    const int w    = tid >> 6;
    const int l15  = lane & 15;
    const int l4   = lane >> 4;
    const int nblk = blockIdx.x & 63;
    const int ksp  = blockIdx.x >> 6;
    const int nbase = nblk * 32;

    for (int i = tid; i < 16384; i += 256) {
        int nl = i >> 9, r = i & 511;
        int t = r >> 7, e = r & 127;
        lt[(t * 32 + nl) * 132 + e] = tab[(nbase + nl) * 512 + r];
    }
    __syncthreads();

    f32x4 ar[4][2], ai[4][2];
    #pragma unroll
    for (int rt = 0; rt < 4; rt++)
        #pragma unroll
        for (int nt = 0; nt < 2; nt++) {
            ar[rt][nt] = (f32x4){0.f, 0.f, 0.f, 0.f};
            ai[rt][nt] = (f32x4){0.f, 0.f, 0.f, 0.f};
        }

    const int p2base = ksp * 2048 + w * 512;
    #pragma unroll 1
    for (int ks = 0; ks < 16; ks++) {
        int p2c = p2base + ks * 32;
        s16x8 afr[4];
        #pragma unroll
        for (int rt = 0; rt < 4; rt++)
            afr[rt] = *(const s16x8*)(d_proj + (rt * 16 + l15) * 16384 + p2c + l4 * 8);
        int p2 = p2c + l4 * 8;
        int x = p2 >> 7, y0 = p2 & 127;
        #pragma unroll
        for (int nt = 0; nt < 2; nt++) {
            int nl = nt * 16 + l15;
            float cA = lt[nl * 132 + x];
            float sA = lt[(32 + nl) * 132 + x];
            const float* cB = &lt[(64 + nl) * 132 + y0];
            const float* sB = &lt[(96 + nl) * 132 + y0];
            s16x8 bc, bs;
            #pragma unroll
            for (int j = 0; j < 8; j++) {
                float cb = cB[j], sb = sB[j];
                bc[j] = f2bf(cA * cb - sA * sb);
                bs[j] = f2bf(sA * cb + cA * sb);
            }
            #pragma unroll
            for (int rt = 0; rt < 4; rt++) {
                ar[rt][nt] = __builtin_amdgcn_mfma_f32_16x16x32_bf16(afr[rt], bc, ar[rt][nt], 0, 0, 0);
                ai[rt][nt] = __builtin_amdgcn_mfma_f32_16x16x32_bf16(afr[rt], bs, ai[rt][nt], 0, 0, 0);
            }
        }
    }
    __syncthreads();   // tables dead; reuse lt as reduce buffer
    float* red = lt;
    #pragma unroll
    for (int rt = 0; rt < 4; rt++)
        #pragma unroll
        for (int nt = 0; nt < 2; nt++)
            #pragma unroll
            for (int jj = 0; jj < 4; jj++) {
                int z = rt * 16 + l4 * 4 + jj;
                int q = nt * 16 + l15;
                red[(w * 64 + z) * 64 + q * 2 + 0] = ar[rt][nt][jj];
                red[(w * 64 + z) * 64 + q * 2 + 1] = ai[rt][nt][jj];
            }
    __syncthreads();
    for (int i = tid; i < 4096; i += 256) {
        int z = i >> 6, q = i & 63;
        float s = red[z * 64 + q] + red[4096 + z * 64 + q] + red[8192 + z * 64 + q] + red[12288 + z * 64 + q];
        part[((ksp * 64 + z) * 2048 + nbase + (q >> 1)) * 2 + (q & 1)] = s;
    }
}

// ---------- kernel 3: sum K-split partials, square, reduce to loss ----------
__global__ void k_loss(const float* __restrict__ part, float* __restrict__ out) {
    int g = blockIdx.x * 256 + threadIdx.x;   // 131072 (z,n) pairs
    int z = g >> 11, n = g & 2047;
    float r = 0.f, im = 0.f;
    #pragma unroll
    for (int ksp = 0; ksp < 8; ksp++) {
        const float2 v = *(const float2*)(part + ((ksp * 64 + z) * 2048 + n) * 2);
        r += v.x; im += v.y;
    }
    float val = r * r + im * im;
    #pragma unroll
    for (int o = 32; o > 0; o >>= 1) val += __shfl_xor(val, o);
    __shared__ float sred[4];
    if ((threadIdx.x & 63) == 0) sred[threadIdx.x >> 6] = val;
    __syncthreads();
    if (threadIdx.x == 0)
        atomicAdd(out, (sred[0] + sred[1] + sred[2] + sred[3]) * (0.5f / 131072.0f));
}

extern "C" void kernel_launch(void* const* d_in, const int* in_sizes, int n_in,
                              void* d_out, int out_size, void* d_ws, size_t ws_size,
                              hipStream_t stream) {
    const float* Bmat  = (const float*)d_in[1];
    const float* W0    = (const float*)d_in[2];
    const float* b0    = (const float*)d_in[3];
    const float* W1    = (const float*)d_in[4];
    const float* b1    = (const float*)d_in[5];
    const float* W2    = (const float*)d_in[6];
    const float* b2    = (const float*)d_in[7];
    const float* W3    = (const float*)d_in[8];
    const float* b3    = (const float*)d_in[9];
    const float* W4    = (const float*)d_in[10];
    const float* b4    = (const float*)d_in[11];
    const float* image = (const float*)d_in[12];
    const float* ktraj = (const float*)d_in[13];

    char* ws = (char*)d_ws;
    short* wbf    = (short*)(ws);                  // 135168 B
    float* brev   = (float*)(ws + (256u << 10));   // 2 KB (prescaled biases)
    float* tab    = (float*)(ws + (1u << 20));     // 4 MB
    float* d_nat  = (float*)(ws + (5u << 20));     // 4 MB
    short* d_proj = (short*)(ws + (9u << 20));     // 2 MB
    float* part   = (float*)(ws + (11u << 20));    // 8 MB
    float* outf   = (float*)d_out;

    hipLaunchKernelGGL(k_prep_w,    dim3(267),  dim3(256), 0, stream,
                       W0, W1, W2, W3, W4, b0, b1, b2, b3, wbf, brev);
    hipLaunchKernelGGL(k_tables,    dim3(2048), dim3(256), 0, stream, ktraj, tab);
    hipLaunchKernelGGL(k_siren,     dim3(4096), dim3(512), 0, stream,
                       Bmat, brev, b4, wbf, image, d_nat);
    hipLaunchKernelGGL(k_transpose, dim3(128),  dim3(256), 0, stream, d_nat, d_proj);
    hipLaunchKernelGGL(k_project,   dim3(512),  dim3(256), 0, stream, d_proj, tab, part);
    hipMemsetAsync(d_out, 0, sizeof(float), stream);
    hipLaunchKernelGGL(k_loss,      dim3(512),  dim3(256), 0, stream, part, outf);
}